// Round 1
// baseline (123.220 us; speedup 1.0000x reference)
//
#include <hip/hip_runtime.h>

// LELoss: scalar loss =
//   mean_B sum_D (x - decoded)^2
// + 1.1 * mean_B sum_E (encoded - latent @ rsrA^T)^2   (lambda1=1.0 plus the
//                                                       duplicated 0.1 "local" term;
//                                                       kNN computation is dead code)
// + 0.1 * mean_{20x20} (rsrA^T rsrA - I)^2
//
// Shapes: x,decoded [8192,1024] f32; encoded [8192,128]; latent [8192,20];
//         rsrA [128,20]. Output: 1 float.

#define BB 8192
#define DD 1024
#define EE 128
#define II 20

__global__ __launch_bounds__(256) void leloss_kernel(
    const float* __restrict__ x,
    const float* __restrict__ encoded,
    const float* __restrict__ latent,
    const float* __restrict__ decoded,
    const float* __restrict__ rsrA,
    float* __restrict__ out)
{
    // rsrA transposed in LDS: sAT[k*EE + e] = rsrA[e*II + k]
    // -> part-B lanes (consecutive e) read stride-1: conflict-free (2 lanes/bank is free)
    __shared__ float sAT[II * EE];
    __shared__ float sred[4];

    const int tid = threadIdx.x;
    for (int t = tid; t < EE * II; t += 256) {
        int e = t / II, k = t - e * II;
        sAT[k * EE + e] = rsrA[t];
    }
    __syncthreads();

    const int gid = blockIdx.x * 256 + tid;
    const int gsz = gridDim.x * 256;

    // ---- Part A: reconstruction MSE, float4 vectorized (64 MB of traffic) ----
    float accA = 0.f;
    {
        const float4* x4 = (const float4*)x;
        const float4* d4 = (const float4*)decoded;
        const int nA = BB * DD / 4;  // 2,097,152
        for (int i = gid; i < nA; i += gsz) {
            float4 a = x4[i], b = d4[i];
            float dx = a.x - b.x, dy = a.y - b.y;
            float dz = a.z - b.z, dw = a.w - b.w;
            accA += dx * dx + dy * dy + dz * dz + dw * dw;
        }
    }

    // ---- Part B: PCA error, one thread per (b,e), dot length 20 ----
    float accB = 0.f;
    {
        const int nB = BB * EE;  // 1,048,576
        for (int i = gid; i < nB; i += gsz) {
            const int b = i >> 7;          // E = 128
            const int e = i & (EE - 1);
            const float* __restrict__ lrow = latent + b * II;
            float z = 0.f;
#pragma unroll
            for (int k = 0; k < II; ++k)
                z = fmaf(lrow[k], sAT[k * EE + e], z);  // lrow broadcast across wave
            const float diff = encoded[i] - z;
            accB += diff * diff;
        }
    }

    // ---- Part C: Gram term (20x20, block 0 only, tiny) ----
    float accC = 0.f;
    if (blockIdx.x == 0) {
        for (int t = tid; t < II * II; t += 256) {
            const int i2 = t / II, j2 = t - i2 * II;
            float g = 0.f;
            for (int e = 0; e < EE; ++e)
                g = fmaf(sAT[i2 * EE + e], sAT[j2 * EE + e], g);
            if (i2 == j2) g -= 1.f;
            accC += g * g;
        }
    }

    float total = accA * (1.0f / BB)
                + accB * (1.1f / BB)              // lambda1 + 0.1
                + accC * (0.1f / (II * II));      // lambda2 / 400

    // ---- reduce: wave64 shuffle, then 4 waves via LDS, one atomic per block ----
#pragma unroll
    for (int off = 32; off > 0; off >>= 1)
        total += __shfl_down(total, off, 64);
    const int wave = tid >> 6, lane = tid & 63;
    if (lane == 0) sred[wave] = total;
    __syncthreads();
    if (tid == 0) {
        atomicAdd(out, sred[0] + sred[1] + sred[2] + sred[3]);
    }
}

extern "C" void kernel_launch(void* const* d_in, const int* in_sizes, int n_in,
                              void* d_out, int out_size, void* d_ws, size_t ws_size,
                              hipStream_t stream) {
    const float* x       = (const float*)d_in[0];
    const float* encoded = (const float*)d_in[1];
    const float* latent  = (const float*)d_in[2];
    const float* decoded = (const float*)d_in[3];
    const float* rsrA    = (const float*)d_in[4];
    float* out = (float*)d_out;

    // d_out is poisoned to 0xAA before every launch; zero it on-stream.
    hipMemsetAsync(out, 0, sizeof(float), stream);

    // 2048 blocks x 256 threads: 8 blocks/CU, 4 float4 iters/thread for part A.
    leloss_kernel<<<2048, 256, 0, stream>>>(x, encoded, latent, decoded, rsrA, out);
}

// Round 2
// 110.817 us; speedup vs baseline: 1.1119x; 1.1119x over previous
//
#include <hip/hip_runtime.h>

// LELoss: scalar loss =
//   mean_B sum_D (x - decoded)^2
// + 1.1 * mean_B sum_E (encoded - latent @ rsrA^T)^2   (lambda1 + duplicated 0.1 term;
//                                                       kNN top-k is dead code)
// + 0.1 * mean_{20x20} (rsrA^T rsrA - I)^2
//
// Shapes fixed by the problem: x,decoded [8192,1024] f32; encoded [8192,128];
// latent [8192,20]; rsrA [128,20]. Output: 1 float.
//
// Structure: K1 (2048 blocks) -> per-block partial in d_ws (plain store, no
// atomics, no init needed) -> K2 (1 block) reduces partials + Gram term and
// plain-stores d_out (no memset node in the graph).

#define BB 8192
#define DD 1024
#define EE 128
#define II 20
#define GRID 2048
#define BLK 256
#define GSZ (GRID * BLK)        // 524288 threads
#define NA (BB * DD / 4)        // 2,097,152 float4s = 4 * GSZ exactly
#define NB (BB * EE)            // 1,048,576        = 2 * GSZ exactly

// Force a wave-uniform pointer into SGPRs so dependent constant-offset loads
// become s_load (scalar cache) instead of 64 redundant per-lane VMEM loads.
__device__ __forceinline__ const float* uniform_ptr(const float* p) {
    unsigned long long v = (unsigned long long)p;
    unsigned lo = __builtin_amdgcn_readfirstlane((unsigned)v);
    unsigned hi = __builtin_amdgcn_readfirstlane((unsigned)(v >> 32));
    return (const float*)(((unsigned long long)hi << 32) | lo);
}

__global__ __launch_bounds__(BLK) void leloss_main(
    const float* __restrict__ x,
    const float* __restrict__ encoded,
    const float* __restrict__ latent,
    const float* __restrict__ decoded,
    const float* __restrict__ rsrA,
    float* __restrict__ partials)
{
    // rsrA transposed in LDS: sAT[k*EE + e] = rsrA[e*II + k]
    __shared__ float sAT[II * EE];
    __shared__ float sred[4];

    const int tid = threadIdx.x;
    const int gid = blockIdx.x * BLK + tid;

    // ---- Part A loads: 4 independent float4 pairs, all in flight at once ----
    const float4* __restrict__ x4 = (const float4*)x;
    const float4* __restrict__ d4 = (const float4*)decoded;
    float4 a0 = x4[gid];
    float4 b0 = d4[gid];
    float4 a1 = x4[gid + GSZ];
    float4 b1 = d4[gid + GSZ];
    float4 a2 = x4[gid + 2 * GSZ];
    float4 b2 = d4[gid + 2 * GSZ];
    float4 a3 = x4[gid + 3 * GSZ];
    float4 b3 = d4[gid + 3 * GSZ];

    // ---- Part B loads: encoded values (coalesced), issued early ----
    const float enc0 = encoded[gid];
    const float enc1 = encoded[gid + GSZ];

    // ---- stage rsrA^T into LDS while global loads are in flight ----
    for (int t = tid; t < EE * II; t += BLK) {
        int e = t / II, k = t - e * II;
        sAT[k * EE + e] = rsrA[t];
    }
    __syncthreads();

    // ---- Part A compute ----
    float accA = 0.f;
    {
        float d;
        d = a0.x - b0.x; accA = fmaf(d, d, accA);
        d = a0.y - b0.y; accA = fmaf(d, d, accA);
        d = a0.z - b0.z; accA = fmaf(d, d, accA);
        d = a0.w - b0.w; accA = fmaf(d, d, accA);
        d = a1.x - b1.x; accA = fmaf(d, d, accA);
        d = a1.y - b1.y; accA = fmaf(d, d, accA);
        d = a1.z - b1.z; accA = fmaf(d, d, accA);
        d = a1.w - b1.w; accA = fmaf(d, d, accA);
        d = a2.x - b2.x; accA = fmaf(d, d, accA);
        d = a2.y - b2.y; accA = fmaf(d, d, accA);
        d = a2.z - b2.z; accA = fmaf(d, d, accA);
        d = a2.w - b2.w; accA = fmaf(d, d, accA);
        d = a3.x - b3.x; accA = fmaf(d, d, accA);
        d = a3.y - b3.y; accA = fmaf(d, d, accA);
        d = a3.z - b3.z; accA = fmaf(d, d, accA);
        d = a3.w - b3.w; accA = fmaf(d, d, accA);
    }

    // ---- Part B: two (b,e) elements per thread; b is wave-uniform ----
    // i0 = gid -> b0r = gid>>7 (uniform per wave since wave base is 64-aligned
    // and e spans halves of 128); i1 = gid + GSZ -> b0r + 4096, same e.
    float accB = 0.f;
    {
        const int e = gid & (EE - 1);
        const int brow = gid >> 7;
        const float* __restrict__ l0 = uniform_ptr(latent + brow * II);
        const float* __restrict__ l1 = uniform_ptr(latent + (brow + (GSZ >> 7)) * II);
        float z0 = 0.f, z1 = 0.f;
#pragma unroll
        for (int k = 0; k < II; ++k) {
            const float w = sAT[k * EE + e];   // stride-1 across lanes
            z0 = fmaf(l0[k], w, z0);           // l0[k]/l1[k] are s_loads
            z1 = fmaf(l1[k], w, z1);
        }
        const float f0 = enc0 - z0;
        const float f1 = enc1 - z1;
        accB = fmaf(f0, f0, fmaf(f1, f1, 0.f));
    }

    float total = accA * (1.0f / BB) + accB * (1.1f / BB);

    // ---- block reduce: wave64 shuffle, 4 waves via LDS, plain store ----
#pragma unroll
    for (int off = 32; off > 0; off >>= 1)
        total += __shfl_down(total, off, 64);
    if ((tid & 63) == 0) sred[tid >> 6] = total;
    __syncthreads();
    if (tid == 0)
        partials[blockIdx.x] = sred[0] + sred[1] + sred[2] + sred[3];
}

__global__ __launch_bounds__(BLK) void leloss_final(
    const float* __restrict__ partials,
    const float* __restrict__ rsrA,
    float* __restrict__ out)
{
    __shared__ float sA[EE * II];
    __shared__ float sred[4];
    const int tid = threadIdx.x;

    // sum the 2048 block partials: 8 independent loads per thread
    float acc = 0.f;
#pragma unroll
    for (int j = 0; j < GRID / BLK; ++j)
        acc += partials[j * BLK + tid];

    // stage rsrA (row-major, 2560 floats) into LDS
    for (int t = tid; t < EE * II; t += BLK) sA[t] = rsrA[t];
    __syncthreads();

    // Gram term: g[i][j] = sum_e A[e][i]*A[e][j]; 400 entries over 256 threads
    float accC = 0.f;
    for (int t = tid; t < II * II; t += BLK) {
        const int i2 = t / II, j2 = t - i2 * II;
        float g = 0.f;
#pragma unroll 4
        for (int e = 0; e < EE; ++e)
            g = fmaf(sA[e * II + i2], sA[e * II + j2], g);
        if (i2 == j2) g -= 1.f;
        accC = fmaf(g, g, accC);
    }

    float total = acc + accC * (0.1f / (II * II));
#pragma unroll
    for (int off = 32; off > 0; off >>= 1)
        total += __shfl_down(total, off, 64);
    if ((tid & 63) == 0) sred[tid >> 6] = total;
    __syncthreads();
    if (tid == 0) out[0] = sred[0] + sred[1] + sred[2] + sred[3];
}

extern "C" void kernel_launch(void* const* d_in, const int* in_sizes, int n_in,
                              void* d_out, int out_size, void* d_ws, size_t ws_size,
                              hipStream_t stream) {
    const float* x       = (const float*)d_in[0];
    const float* encoded = (const float*)d_in[1];
    const float* latent  = (const float*)d_in[2];
    const float* decoded = (const float*)d_in[3];
    const float* rsrA    = (const float*)d_in[4];
    float* out      = (float*)d_out;
    float* partials = (float*)d_ws;   // 2048 floats; all slots written by K1

    leloss_main<<<GRID, BLK, 0, stream>>>(x, encoded, latent, decoded, rsrA, partials);
    leloss_final<<<1, BLK, 0, stream>>>(partials, rsrA, out);
}

// Round 3
// 106.804 us; speedup vs baseline: 1.1537x; 1.0376x over previous
//
#include <hip/hip_runtime.h>

// LELoss: scalar loss =
//   mean_B sum_D (x - decoded)^2
// + 1.1 * mean_B sum_E (encoded - latent @ rsrA^T)^2   (lambda1 + duplicated 0.1 term;
//                                                       kNN top-k is dead code)
// + 0.1 * mean_{20x20} (rsrA^T rsrA - I)^2
//
// Shapes fixed: x,decoded [8192,1024] f32; encoded [8192,128]; latent [8192,20];
// rsrA [128,20]. Output: 1 float.
//
// Structure: K1 (2048 blocks) computes parts A+B everywhere and folds the tiny
// Gram term into block 0's partial (its ~3us of VALU/LDS work hides inside
// block 0's own global-load stalls). K2 (1 block) only sums the 2048 partials.
// No atomics (R1 measured ~15us same-address RMW tail), no memset nodes.

#define BB 8192
#define DD 1024
#define EE 128
#define EEP 129                 // sAT leading-dim pad: breaks stride-128 bank aliasing
#define II 20
#define GRID 2048
#define BLK 256
#define GSZ (GRID * BLK)        // 524288 threads; A: 4 float4-pairs/thread, B: 2 elems/thread

// Force a wave-uniform pointer into SGPRs so constant-offset loads become
// s_load (scalar path) instead of 64 redundant per-lane VMEM loads.
__device__ __forceinline__ const float* uniform_ptr(const float* p) {
    unsigned long long v = (unsigned long long)p;
    unsigned lo = __builtin_amdgcn_readfirstlane((unsigned)v);
    unsigned hi = __builtin_amdgcn_readfirstlane((unsigned)(v >> 32));
    return (const float*)(((unsigned long long)hi << 32) | lo);
}

__global__ __launch_bounds__(BLK) void leloss_main(
    const float* __restrict__ x,
    const float* __restrict__ encoded,
    const float* __restrict__ latent,
    const float* __restrict__ decoded,
    const float* __restrict__ rsrA,
    float* __restrict__ partials)
{
    // rsrA transposed in LDS: sAT[k*EEP + e] = rsrA[e*II + k]
    // Part B: lanes vary e -> consecutive banks (conflict-free).
    // Gram:   lanes vary i2, fixed e -> bank (i2*129+e)%32 varies with i2 (conflict-free).
    __shared__ float sAT[II * EEP];
    __shared__ float sred[4];

    const int tid = threadIdx.x;
    const int gid = blockIdx.x * BLK + tid;

    // ---- Part A loads: 4 independent float4 pairs, all in flight at once ----
    const float4* __restrict__ x4 = (const float4*)x;
    const float4* __restrict__ d4 = (const float4*)decoded;
    float4 a0 = x4[gid];
    float4 b0 = d4[gid];
    float4 a1 = x4[gid + GSZ];
    float4 b1 = d4[gid + GSZ];
    float4 a2 = x4[gid + 2 * GSZ];
    float4 b2 = d4[gid + 2 * GSZ];
    float4 a3 = x4[gid + 3 * GSZ];
    float4 b3 = d4[gid + 3 * GSZ];

    // ---- Part B loads: coalesced, issued early ----
    const float enc0 = encoded[gid];
    const float enc1 = encoded[gid + GSZ];

    // ---- stage rsrA^T into LDS while global loads are in flight ----
    for (int t = tid; t < EE * II; t += BLK) {
        int e = t / II, k = t - e * II;
        sAT[k * EEP + e] = rsrA[t];
    }
    __syncthreads();

    // ---- Gram term: block 0 only; overlaps block 0's global-load latency ----
    float accC = 0.f;
    if (blockIdx.x == 0) {
        for (int t = tid; t < II * II; t += BLK) {
            const int i2 = t / II, j2 = t - i2 * II;
            float g = 0.f;
#pragma unroll 8
            for (int e = 0; e < EE; ++e)
                g = fmaf(sAT[i2 * EEP + e], sAT[j2 * EEP + e], g);
            if (i2 == j2) g -= 1.f;
            accC = fmaf(g, g, accC);
        }
    }

    // ---- Part A compute ----
    float accA = 0.f;
    {
        float d;
        d = a0.x - b0.x; accA = fmaf(d, d, accA);
        d = a0.y - b0.y; accA = fmaf(d, d, accA);
        d = a0.z - b0.z; accA = fmaf(d, d, accA);
        d = a0.w - b0.w; accA = fmaf(d, d, accA);
        d = a1.x - b1.x; accA = fmaf(d, d, accA);
        d = a1.y - b1.y; accA = fmaf(d, d, accA);
        d = a1.z - b1.z; accA = fmaf(d, d, accA);
        d = a1.w - b1.w; accA = fmaf(d, d, accA);
        d = a2.x - b2.x; accA = fmaf(d, d, accA);
        d = a2.y - b2.y; accA = fmaf(d, d, accA);
        d = a2.z - b2.z; accA = fmaf(d, d, accA);
        d = a2.w - b2.w; accA = fmaf(d, d, accA);
        d = a3.x - b3.x; accA = fmaf(d, d, accA);
        d = a3.y - b3.y; accA = fmaf(d, d, accA);
        d = a3.z - b3.z; accA = fmaf(d, d, accA);
        d = a3.w - b3.w; accA = fmaf(d, d, accA);
    }

    // ---- Part B: two (b,e) elements per thread; b row wave-uniform ----
    float accB = 0.f;
    {
        const int e = gid & (EE - 1);
        const int brow = gid >> 7;   // uniform per wave (wave spans half of E=128)
        const float* __restrict__ l0 = uniform_ptr(latent + brow * II);
        const float* __restrict__ l1 = uniform_ptr(latent + (brow + (GSZ >> 7)) * II);
        float z0 = 0.f, z1 = 0.f;
#pragma unroll
        for (int k = 0; k < II; ++k) {
            const float w = sAT[k * EEP + e];  // consecutive banks across lanes
            z0 = fmaf(l0[k], w, z0);           // s_load scalar reads
            z1 = fmaf(l1[k], w, z1);
        }
        const float f0 = enc0 - z0;
        const float f1 = enc1 - z1;
        accB = fmaf(f0, f0, fmaf(f1, f1, 0.f));
    }

    float total = accA * (1.0f / BB)
                + accB * (1.1f / BB)
                + accC * (0.1f / (II * II));

    // ---- block reduce: wave64 shuffle, 4 waves via LDS, plain store ----
#pragma unroll
    for (int off = 32; off > 0; off >>= 1)
        total += __shfl_down(total, off, 64);
    if ((tid & 63) == 0) sred[tid >> 6] = total;
    __syncthreads();
    if (tid == 0)
        partials[blockIdx.x] = sred[0] + sred[1] + sred[2] + sred[3];
}

__global__ __launch_bounds__(BLK) void leloss_final(
    const float* __restrict__ partials,
    float* __restrict__ out)
{
    __shared__ float sred[4];
    const int tid = threadIdx.x;

    float acc = 0.f;
#pragma unroll
    for (int j = 0; j < GRID / BLK; ++j)
        acc += partials[j * BLK + tid];

#pragma unroll
    for (int off = 32; off > 0; off >>= 1)
        acc += __shfl_down(acc, off, 64);
    if ((tid & 63) == 0) sred[tid >> 6] = acc;
    __syncthreads();
    if (tid == 0) out[0] = sred[0] + sred[1] + sred[2] + sred[3];
}

extern "C" void kernel_launch(void* const* d_in, const int* in_sizes, int n_in,
                              void* d_out, int out_size, void* d_ws, size_t ws_size,
                              hipStream_t stream) {
    const float* x       = (const float*)d_in[0];
    const float* encoded = (const float*)d_in[1];
    const float* latent  = (const float*)d_in[2];
    const float* decoded = (const float*)d_in[3];
    const float* rsrA    = (const float*)d_in[4];
    float* out      = (float*)d_out;
    float* partials = (float*)d_ws;   // 2048 floats; every slot written by K1

    leloss_main<<<GRID, BLK, 0, stream>>>(x, encoded, latent, decoded, rsrA, partials);
    leloss_final<<<1, BLK, 0, stream>>>(partials, out);
}